// Round 9
// baseline (1934.548 us; speedup 1.0000x reference)
//
#include <hip/hip_runtime.h>
#include <hip/hip_bf16.h>

// DeepSeek V3 MLA attention forward, MI355X (gfx950).
// B=2, S=2048, D=2048, H=16, NOPE=128, ROPE=64, VDIM=128, QKD=192.

typedef __bf16 bf16x8 __attribute__((ext_vector_type(8)));
typedef float floatx4 __attribute__((ext_vector_type(4)));
#define BF16 __hip_bfloat16

static __device__ __forceinline__ BF16 f2b(float x) { return __float2bfloat16(x); }
static __device__ __forceinline__ unsigned short b2u(BF16 x) { return *(unsigned short*)&x; }
static __device__ __forceinline__ float fast_exp2(float x) { return __builtin_amdgcn_exp2f(x); }

// DPP cross-lane move within a 16-lane row (VALU pipe, ~8 cyc vs ~60+ for ds_swizzle).
template<int CTRL>
static __device__ __forceinline__ float dpp_mov(float x) {
  int xi = __builtin_bit_cast(int, x);
  int yi = __builtin_amdgcn_update_dpp(xi, xi, CTRL, 0xF, 0xF, false);
  return __builtin_bit_cast(float, yi);
}
// all-reduce across the 16 lanes of a DPP row: xor1, xor2, half-mirror, mirror
static __device__ __forceinline__ float row_allmax(float x) {
  x = fmaxf(x, dpp_mov<0xB1>(x));   // quad_perm [1,0,3,2]
  x = fmaxf(x, dpp_mov<0x4E>(x));   // quad_perm [2,3,0,1]
  x = fmaxf(x, dpp_mov<0x141>(x));  // row_half_mirror
  x = fmaxf(x, dpp_mov<0x140>(x));  // row_mirror
  return x;
}
static __device__ __forceinline__ float row_allsum(float x) {
  x += dpp_mov<0xB1>(x);
  x += dpp_mov<0x4E>(x);
  x += dpp_mov<0x141>(x);
  x += dpp_mov<0x140>(x);
  return x;
}

static __device__ __forceinline__ void load_lds16(const BF16* g, BF16* l) {
  __builtin_amdgcn_global_load_lds((__attribute__((address_space(1))) void*)(void*)g,
                                   (__attribute__((address_space(3))) void*)(void*)l,
                                   16, 0, 0);
}

// ---------------------------------------------------------------- multi-region cast f32->bf16
struct CastArgs {
  const float* src[6];
  BF16* dst[6];
  long n[6];
};
__global__ void cast_multi_k(CastArgs a) {
  int r = blockIdx.y;
  long n = a.n[r];
  const float* __restrict__ x = a.src[r];
  BF16* __restrict__ y = a.dst[r];
  for (long i = ((long)blockIdx.x * 256 + threadIdx.x) * 4; i + 3 < n;
       i += (long)gridDim.x * 1024) {
    float4 v = *(const float4*)(x + i);
    y[i+0] = f2b(v.x); y[i+1] = f2b(v.y); y[i+2] = f2b(v.z); y[i+3] = f2b(v.w);
  }
}

// ---------------------------------------------------------------- NT GEMM body, m97-style LDS staging
// C[M][N] = A[M][K]*B[N][K]^T. 256 thr = 4 waves (2x2), 128x128 tile, BK=32.
// OUT_MODE: 0 = fp32 C;  2 = kv scatter -> Kt (scalar) / Vt transposed (8B packed);
//           3 = q RoPE+scale scatter -> Qt (scale includes log2(e) for exp2 softmax).
template<int OUT_MODE>
static __device__ __forceinline__ void gemm_body(
    const BF16* __restrict__ A, const BF16* __restrict__ B, void* __restrict__ C,
    int M, int N, int K, const float* __restrict__ cosb, const float* __restrict__ sinb,
    BF16* __restrict__ P1, BF16* __restrict__ P2, int bx, int by, BF16* As, BF16* Bs) {
  int tid = threadIdx.x, wave = tid >> 6, lane = tid & 63;
  int wr = wave >> 1, wc = wave & 1, lr = lane & 15, quad = lane >> 4;
  long m0 = (long)by * 128, n0 = (long)bx * 128;

  int c0 = wave*64 + lane, c1 = c0 + 256;
  const BF16* ga0 = A + (m0 + (c0>>2))*(long)K + (c0&3)*8;
  const BF16* ga1 = A + (m0 + (c1>>2))*(long)K + (c1&3)*8;
  long bn0 = n0 + (c0>>2); if (bn0 >= N) bn0 = N-1;
  long bn1 = n0 + (c1>>2); if (bn1 >= N) bn1 = N-1;
  const BF16* gb0 = B + bn0*(long)K + (c0&3)*8;
  const BF16* gb1 = B + bn1*(long)K + (c1&3)*8;
  BF16* la0 = As + wave*512;
  BF16* la1 = As + wave*512 + 2048;
  BF16* lb0 = Bs + wave*512;
  BF16* lb1 = Bs + wave*512 + 2048;

  floatx4 acc[4][4] = {};
  for (int k0 = 0; k0 < K; k0 += 32) {
    __syncthreads();
    load_lds16(ga0 + k0, la0);
    load_lds16(ga1 + k0, la1);
    load_lds16(gb0 + k0, lb0);
    load_lds16(gb1 + k0, lb1);
    __syncthreads();
    bf16x8 a[4], b[4];
#pragma unroll
    for (int i = 0; i < 4; i++) a[i] = *(const bf16x8*)(As + (wr*64 + i*16 + lr)*32 + quad*8);
#pragma unroll
    for (int j = 0; j < 4; j++) b[j] = *(const bf16x8*)(Bs + (wc*64 + j*16 + lr)*32 + quad*8);
#pragma unroll
    for (int i = 0; i < 4; i++)
#pragma unroll
      for (int j = 0; j < 4; j++)
        acc[i][j] = __builtin_amdgcn_mfma_f32_16x16x32_bf16(a[i], b[j], acc[i][j], 0, 0, 0);
  }

  long n0w = n0 + wc*64;
  // 192^-0.5 * log2(e): softmax runs in exp2 domain.
  const float SCALE_L2E = 0.104117546f;
#pragma unroll
  for (int i = 0; i < 4; i++) {
    long tok = m0 + wr*64 + i*16 + quad*4;   // 4 consecutive tokens (r=0..3)
    long bb = tok >> 11, s = tok & 2047;
    if (OUT_MODE == 0) {
#pragma unroll
      for (int r = 0; r < 4; r++) {
        long row = tok + r;
#pragma unroll
        for (int j = 0; j < 4; j++) {
          long col = n0w + j*16 + lr;
          if (col < N) ((float*)C)[row*(long)N + col] = acc[i][j][r];
        }
      }
    } else if (OUT_MODE == 2) {
#pragma unroll
      for (int j = 0; j < 4; j++) {
        long col = n0w + j*16 + lr;
        long h = col >> 8, d = col & 255;
        if (d < 128) {
#pragma unroll
          for (int r = 0; r < 4; r++)
            P1[((bb*16 + h)*2048 + s + r)*192 + d] = f2b(acc[i][j][r]);
        } else {
          // Vt transposed (B,H,128,2048): 4 consecutive tokens packed, 8B store
          ushort4 pk;
          pk.x = b2u(f2b(acc[i][j][0])); pk.y = b2u(f2b(acc[i][j][1]));
          pk.z = b2u(f2b(acc[i][j][2])); pk.w = b2u(f2b(acc[i][j][3]));
          *(ushort4*)(P2 + ((bb*16 + h)*128 + d - 128)*2048 + s) = pk;
        }
      }
    } else { // OUT_MODE == 3: q RoPE + scale -> Qt (B,H,S,192)
      bool rope = ((n0w % 192) == 128);
#pragma unroll
      for (int r = 0; r < 4; r++) {
        long row = tok + r;
#pragma unroll
        for (int j = 0; j < 4; j++) {
          long col = n0w + j*16 + lr;
          float x = acc[i][j][r], val;
          if (rope) {
            int id = j*16 + lr;
            float partner = acc[i][j^2][r];
            float rot = (j < 2) ? -partner : partner;
            val = x*cosb[row*64 + id] + rot*sinb[row*64 + id];
          } else {
            val = x;
          }
          long h = col / 192, d = col % 192;
          P1[((bb*16 + h)*2048 + s + r)*192 + d] = f2b(val * SCALE_L2E);
        }
      }
    }
  }
}

__global__ __launch_bounds__(256) void gemm0_k(const BF16* __restrict__ A, const BF16* __restrict__ B,
                                               float* __restrict__ C, int M, int N, int K) {
  __shared__ __align__(16) BF16 As[128*32];
  __shared__ __align__(16) BF16 Bs[128*32];
  gemm_body<0>(A, B, C, M, N, K, nullptr, nullptr, nullptr, nullptr,
               blockIdx.x, blockIdx.y, As, Bs);
}

// q_b (768 blocks, mode 3) + kv_b (1024 blocks, mode 2) in one launch: tails overlap.
__global__ __launch_bounds__(256) void gemm_qkv_k(const BF16* __restrict__ qan, const BF16* __restrict__ Wqb,
                                                  const BF16* __restrict__ kvn, const BF16* __restrict__ Wkvb,
                                                  const float* __restrict__ cosb, const float* __restrict__ sinb,
                                                  BF16* __restrict__ Qt, BF16* __restrict__ Kt,
                                                  BF16* __restrict__ Vt) {
  __shared__ __align__(16) BF16 As[128*32];
  __shared__ __align__(16) BF16 Bs[128*32];
  int bid = blockIdx.x;
  if (bid < 768) {
    gemm_body<3>(qan, Wqb, nullptr, 4096, 3072, 1536, cosb, sinb, Qt, nullptr,
                 bid % 24, bid / 24, As, Bs);
  } else {
    bid -= 768;
    gemm_body<2>(kvn, Wkvb, nullptr, 4096, 4096, 512, nullptr, nullptr, Kt, Vt,
                 bid % 32, bid / 32, As, Bs);
  }
}

// ---------------------------------------------------------------- fused: rmsnorm(1536) + rmsnorm(512) + k_rot RoPE
// One block per token row of qakv (stride 2112: [q_a 1536 | ckv 512 | krot 64]).
__global__ __launch_bounds__(256) void norms_k(const float* __restrict__ qakv,
                                               const float* __restrict__ qw, const float* __restrict__ kw,
                                               const float* __restrict__ cosb, const float* __restrict__ sinb,
                                               BF16* __restrict__ qan, BF16* __restrict__ kvn,
                                               BF16* __restrict__ Kt) {
  long row = blockIdx.x;
  const float* xr = qakv + row * 2112;
  int tid = threadIdx.x;
  __shared__ float red[4];
  // ---- rmsnorm D=1536 -> qan
  {
    float ss = 0.f;
    for (int i = tid*4; i < 1536; i += 1024) {
      float4 v = *(const float4*)(xr + i);
      ss += v.x*v.x + v.y*v.y + v.z*v.z + v.w*v.w;
    }
#pragma unroll
    for (int off = 32; off > 0; off >>= 1) ss += __shfl_down(ss, off);
    if ((tid & 63) == 0) red[tid >> 6] = ss;
    __syncthreads();
    float rs = rsqrtf((red[0]+red[1]+red[2]+red[3]) / 1536.f + 1e-6f);
    BF16* yr = qan + row * 1536;
    for (int i = tid*4; i < 1536; i += 1024) {
      float4 v = *(const float4*)(xr + i);
      yr[i+0] = f2b(v.x * qw[i+0] * rs);
      yr[i+1] = f2b(v.y * qw[i+1] * rs);
      yr[i+2] = f2b(v.z * qw[i+2] * rs);
      yr[i+3] = f2b(v.w * qw[i+3] * rs);
    }
  }
  __syncthreads();
  // ---- rmsnorm D=512 (offset 1536) -> kvn
  {
    float ss = 0.f;
    for (int i = tid*4; i < 512; i += 1024) {
      float4 v = *(const float4*)(xr + 1536 + i);
      ss += v.x*v.x + v.y*v.y + v.z*v.z + v.w*v.w;
    }
#pragma unroll
    for (int off = 32; off > 0; off >>= 1) ss += __shfl_down(ss, off);
    if ((tid & 63) == 0) red[tid >> 6] = ss;
    __syncthreads();
    float rs = rsqrtf((red[0]+red[1]+red[2]+red[3]) / 512.f + 1e-6f);
    BF16* yr = kvn + row * 512;
    for (int i = tid*4; i < 512; i += 1024) {
      float4 v = *(const float4*)(xr + 1536 + i);
      yr[i+0] = f2b(v.x * kw[i+0] * rs);
      yr[i+1] = f2b(v.y * kw[i+1] * rs);
      yr[i+2] = f2b(v.z * kw[i+2] * rs);
      yr[i+3] = f2b(v.w * kw[i+3] * rs);
    }
  }
  // ---- k_rot RoPE -> Kt[...,128:192] broadcast to all 16 heads
  if (tid < 64) {
    int i = tid;
    const float* kr = xr + 2048;
    float x = kr[i];
    float rot = (i < 32) ? -kr[i + 32] : kr[i - 32];
    BF16 v = f2b(x * cosb[row*64 + i] + rot * sinb[row*64 + i]);
    long b = row >> 11, s = row & 2047;
    long base = ((b*16)*2048 + s)*192 + 128 + i;
#pragma unroll
    for (int h = 0; h < 16; h++) Kt[base + (long)h*2048*192] = v;
  }
}

// ---------------------------------------------------------------- causal flash attention
// grid 256, 512 threads (8 waves); g = F&31 = (b,h) group (XCD pin: F%8 = g%8);
// j = F>>5 in 0..7: block handles 128-row q-tile pair {j, 15-j} -> 34 uniform
// k-tile iters. Each wave owns 16 q-rows; waves fully below the diagonal skip
// compute (barriers stay unconditional). Q prescaled by 192^-0.5*log2e; V is
// (B,H,128,S) transposed so staging is b128-only, bank-uniform.
// Softmax reductions use DPP row all-reduce (VALU) — no LDS swizzle latency.
// Staging uses depth-2 register prefetch to cover HBM-miss latency.
#define LK 200
#define LV 72
#define LP 72
__global__ __launch_bounds__(512) void flash_k(const BF16* __restrict__ Qt, const BF16* __restrict__ Kt,
                                               const BF16* __restrict__ Vt, BF16* __restrict__ O) {
  __shared__ __align__(16) BF16 Ks[64*LK];    // K tile [kpos][d]        25.6 KB
  __shared__ __align__(16) BF16 Vs[128*LV];   // V^T tile [vd][kpos]     18.4 KB
  __shared__ __align__(16) BF16 Ps[8][16*LP]; // per-wave P [q16][kpos]  18.4 KB
  int tid = threadIdx.x, wave = tid >> 6, lane = tid & 63;
  int lr = lane & 15, quad = lane >> 4;
  int F = blockIdx.x;
  int g = F & 31, j = F >> 5;
  int h = g & 15, b = g >> 4;
  const BF16* Qb = Qt + ((long)(b*16 + h) * 2048) * 192;
  const BF16* Kb = Kt + ((long)(b*16 + h) * 2048) * 192;
  const BF16* Vb = Vt + ((long)(b*16 + h) * 128) * 2048;
  const float NEG_INF = -__builtin_inff();

  // staging geometry: K 1536 chunks / 512 thr = 3; V 1024 chunks / 512 thr = 2
  int krow[3], kcol[3];
#pragma unroll
  for (int i = 0; i < 3; i++) {
    int c = tid + 512*i;
    krow[i] = c / 24; kcol[i] = (c % 24) * 8;
  }
  int vrow[2], vcol[2];
#pragma unroll
  for (int i = 0; i < 2; i++) {
    int c = tid + 512*i;
    vrow[i] = c >> 3; vcol[i] = (c & 7) * 8;
  }

  bf16x8 kreg[2][3], vreg[2][2];   // depth-2 prefetch buffers
  auto stage_load = [&](int p, int k0) {
#pragma unroll
    for (int i = 0; i < 3; i++)
      kreg[p][i] = *(const bf16x8*)(Kb + (long)(k0 + krow[i])*192 + kcol[i]);
#pragma unroll
    for (int i = 0; i < 2; i++)
      vreg[p][i] = *(const bf16x8*)(Vb + (long)vrow[i]*2048 + k0 + vcol[i]);
  };
  auto stage_store = [&](int p) {
#pragma unroll
    for (int i = 0; i < 3; i++)
      *(bf16x8*)(Ks + krow[i]*LK + kcol[i]) = kreg[p][i];
#pragma unroll
    for (int i = 0; i < 2; i++)
      *(bf16x8*)(Vs + vrow[i]*LV + vcol[i]) = vreg[p][i];
  };

  for (int half = 0; half < 2; half++) {
    int qt = (half == 0) ? j : 15 - j;
    int q0 = qt * 128;
    int wq0 = q0 + wave*16;   // this wave's first q-row
    bf16x8 qf[6];
    {
      const BF16* qp = Qb + (long)(wq0 + lr) * 192 + quad*8;
#pragma unroll
      for (int f = 0; f < 6; f++) qf[f] = *(const bf16x8*)(qp + f*32);
    }
    float m_i[4], l_i[4];
#pragma unroll
    for (int r = 0; r < 4; r++) { m_i[r] = NEG_INF; l_i[r] = 0.f; }
    floatx4 o_acc[8] = {};
    int nk = 2*qt + 2;   // >= 2 always
    stage_load(0, 0);
    stage_load(1, 64);
    for (int kt = 0; kt < nk; kt++) {
      __syncthreads();   // prev-iter LDS reads complete
      stage_store(kt & 1);
      __syncthreads();
      if (kt + 2 < nk) stage_load(kt & 1, (kt + 2) * 64);  // depth-2 prefetch
      if (kt*64 > wq0 + 15) continue;  // wave fully above diagonal (masked out)
      floatx4 st[4];
#pragma unroll
      for (int t = 0; t < 4; t++) {
        floatx4 c = {};
#pragma unroll
        for (int f = 0; f < 6; f++) {
          bf16x8 kf = *(const bf16x8*)(Ks + (t*16+lr)*LK + f*32 + quad*8);
          c = __builtin_amdgcn_mfma_f32_16x16x32_bf16(qf[f], kf, c, 0, 0, 0);
        }
        st[t] = c;
      }
      float mt[4];
#pragma unroll
      for (int r = 0; r < 4; r++) mt[r] = NEG_INF;
      if (kt*64 + 63 > wq0) { // diagonal k-tile for this wave: causal mask
        int rbase = wq0 + quad*4 - kt*64;  // row - kbase
#pragma unroll
        for (int t = 0; t < 4; t++) {
          int coff = t*16 + lr;
#pragma unroll
          for (int r = 0; r < 4; r++) {
            float sc = st[t][r];
            if (coff > rbase + r) sc = NEG_INF;
            st[t][r] = sc;
            mt[r] = fmaxf(mt[r], sc);
          }
        }
      } else {
#pragma unroll
        for (int t = 0; t < 4; t++)
#pragma unroll
          for (int r = 0; r < 4; r++) mt[r] = fmaxf(mt[r], st[t][r]);
      }
#pragma unroll
      for (int r = 0; r < 4; r++) mt[r] = row_allmax(mt[r]);
      float alpha[4], rsum[4];
#pragma unroll
      for (int r = 0; r < 4; r++) {
        float mn = fmaxf(m_i[r], mt[r]);
        alpha[r] = fast_exp2(m_i[r] - mn);
        m_i[r] = mn;
        rsum[r] = 0.f;
      }
#pragma unroll
      for (int t = 0; t < 4; t++)
#pragma unroll
        for (int r = 0; r < 4; r++) {
          float p = fast_exp2(st[t][r] - m_i[r]);
          st[t][r] = p;
          rsum[r] += p;
        }
#pragma unroll
      for (int r = 0; r < 4; r++) rsum[r] = row_allsum(rsum[r]);
#pragma unroll
      for (int r = 0; r < 4; r++) l_i[r] = l_i[r]*alpha[r] + rsum[r];
#pragma unroll
      for (int v = 0; v < 8; v++)
#pragma unroll
        for (int r = 0; r < 4; r++) o_acc[v][r] *= alpha[r];
      // P (C-layout) -> wave-private LDS -> A-layout (no barrier: wave-level ordering)
#pragma unroll
      for (int t = 0; t < 4; t++)
#pragma unroll
        for (int r = 0; r < 4; r++)
          Ps[wave][(quad*4 + r)*LP + t*16 + lr] = f2b(st[t][r]);
#pragma unroll
      for (int kc = 0; kc < 2; kc++) {
        bf16x8 pa = *(const bf16x8*)(&Ps[wave][lr*LP + kc*32 + quad*8]);
#pragma unroll
        for (int v = 0; v < 8; v++) {
          bf16x8 vf = *(const bf16x8*)(&Vs[(v*16+lr)*LV + kc*32 + quad*8]);
          o_acc[v] = __builtin_amdgcn_mfma_f32_16x16x32_bf16(pa, vf, o_acc[v], 0, 0, 0);
        }
      }
    }
    // epilogue: attn out (B,S,H*128) bf16
    long rowb = wq0 + quad*4;
#pragma unroll
    for (int v = 0; v < 8; v++)
#pragma unroll
      for (int r = 0; r < 4; r++) {
        long row = rowb + r;
        O[((long)b*2048 + row)*2048 + h*128 + v*16 + lr] = f2b(o_acc[v][r] / l_i[r]);
      }
  }
}

// ---------------------------------------------------------------- launch
extern "C" void kernel_launch(void* const* d_in, const int* in_sizes, int n_in,
                              void* d_out, int out_size, void* d_ws, size_t ws_size,
                              hipStream_t stream) {
  const float* hidden      = (const float*)d_in[0];
  const float* cosb        = (const float*)d_in[1];
  const float* sinb        = (const float*)d_in[2];
  const float* q_a_W       = (const float*)d_in[3];
  const float* q_a_norm_w  = (const float*)d_in[4];
  const float* q_b_W       = (const float*)d_in[5];
  const float* kv_a_W      = (const float*)d_in[6];
  const float* kv_a_norm_w = (const float*)d_in[7];
  const float* kv_b_W      = (const float*)d_in[8];
  const float* o_W         = (const float*)d_in[9];
  float* out = (float*)d_out;

  const int Mrows = 4096;

  char* ws = (char*)d_ws; size_t off = 0;
  auto alloc = [&](size_t bytes) -> void* {
    void* p = ws + off; off = (off + bytes + 255) & ~(size_t)255; return p;
  };
  BF16* hb    = (BF16*)alloc((size_t)4096*2048*2);
  BF16* Wqakv = (BF16*)alloc((size_t)2112*2048*2);   // rows 0..1536 = q_a_W, 1536..2112 = kv_a_W
  BF16* Wqb   = (BF16*)alloc((size_t)3072*1536*2);
  BF16* Wkvb  = (BF16*)alloc((size_t)4096*512*2);
  BF16* Wo    = (BF16*)alloc((size_t)2048*2048*2);
  float* qakv = (float*)alloc((size_t)4096*2112*4);  // cols 0..1536 = q_a out, 1536..2112 = ckv
  BF16* qan   = (BF16*)alloc((size_t)4096*1536*2);
  BF16* kvn   = (BF16*)alloc((size_t)4096*512*2);
  BF16* Qt    = (BF16*)alloc((size_t)2*16*2048*192*2);
  BF16* Kt    = (BF16*)alloc((size_t)2*16*2048*192*2);
  BF16* Vt    = (BF16*)alloc((size_t)2*16*128*2048*2); // transposed (B,H,128,S)
  BF16* attn  = (BF16*)alloc((size_t)4096*2048*2);

  CastArgs ca;
  ca.src[0] = hidden;  ca.dst[0] = hb;                 ca.n[0] = (long)4096*2048;
  ca.src[1] = q_a_W;   ca.dst[1] = Wqakv;              ca.n[1] = (long)1536*2048;
  ca.src[2] = kv_a_W;  ca.dst[2] = Wqakv + (long)1536*2048; ca.n[2] = (long)576*2048;
  ca.src[3] = q_b_W;   ca.dst[3] = Wqb;                ca.n[3] = (long)3072*1536;
  ca.src[4] = kv_b_W;  ca.dst[4] = Wkvb;               ca.n[4] = (long)4096*512;
  ca.src[5] = o_W;     ca.dst[5] = Wo;                 ca.n[5] = (long)2048*2048;
  cast_multi_k<<<dim3(1024, 6), dim3(256), 0, stream>>>(ca);

  // [q_a | ckv] = hidden @ [q_a_W | kv_a_W].T  (4096 x 2112, K=2048), fp32
  gemm0_k<<<dim3(17, 32), dim3(256), 0, stream>>>(hb, Wqakv, qakv, Mrows, 2112, 2048);

  // fused rmsnorms + k_rot RoPE
  norms_k<<<dim3(4096), dim3(256), 0, stream>>>(qakv, q_a_norm_w, kv_a_norm_w,
                                                cosb, sinb, qan, kvn, Kt);

  // q_b (RoPE+scale -> Qt) and kv_b (scatter -> Kt / Vt^T) in one launch
  gemm_qkv_k<<<dim3(1792), dim3(256), 0, stream>>>(qan, Wqb, kvn, Wkvb, cosb, sinb, Qt, Kt, Vt);

  flash_k<<<dim3(256), dim3(512), 0, stream>>>(Qt, Kt, Vt, attn);

  // out = attn @ o_W.T (4096x2048, K=2048), fp32 -> d_out
  gemm0_k<<<dim3(16, 32), dim3(256), 0, stream>>>(attn, Wo, out, Mrows, 2048, 2048);
}

// Round 10
// 477.527 us; speedup vs baseline: 4.0512x; 4.0512x over previous
//
#include <hip/hip_runtime.h>
#include <hip/hip_bf16.h>

// DeepSeek V3 MLA attention forward, MI355X (gfx950).
// B=2, S=2048, D=2048, H=16, NOPE=128, ROPE=64, VDIM=128, QKD=192.

typedef __bf16 bf16x8 __attribute__((ext_vector_type(8)));
typedef float floatx4 __attribute__((ext_vector_type(4)));
#define BF16 __hip_bfloat16

static __device__ __forceinline__ BF16 f2b(float x) { return __float2bfloat16(x); }
static __device__ __forceinline__ unsigned short b2u(BF16 x) { return *(unsigned short*)&x; }
static __device__ __forceinline__ float fast_exp2(float x) { return __builtin_amdgcn_exp2f(x); }

// DPP cross-lane move within a 16-lane row (VALU pipe, ~8 cyc vs ~60+ for ds_swizzle).
template<int CTRL>
static __device__ __forceinline__ float dpp_mov(float x) {
  int xi = __builtin_bit_cast(int, x);
  int yi = __builtin_amdgcn_update_dpp(xi, xi, CTRL, 0xF, 0xF, false);
  return __builtin_bit_cast(float, yi);
}
// all-reduce across the 16 lanes of a DPP row: quad xor1, quad xor2, half-mirror, mirror
static __device__ __forceinline__ float row_allmax(float x) {
  x = fmaxf(x, dpp_mov<0xB1>(x));   // quad_perm [1,0,3,2]
  x = fmaxf(x, dpp_mov<0x4E>(x));   // quad_perm [2,3,0,1]
  x = fmaxf(x, dpp_mov<0x141>(x));  // row_half_mirror
  x = fmaxf(x, dpp_mov<0x140>(x));  // row_mirror
  return x;
}
static __device__ __forceinline__ float row_allsum(float x) {
  x += dpp_mov<0xB1>(x);
  x += dpp_mov<0x4E>(x);
  x += dpp_mov<0x141>(x);
  x += dpp_mov<0x140>(x);
  return x;
}

static __device__ __forceinline__ void load_lds16(const BF16* g, BF16* l) {
  __builtin_amdgcn_global_load_lds((__attribute__((address_space(1))) void*)(void*)g,
                                   (__attribute__((address_space(3))) void*)(void*)l,
                                   16, 0, 0);
}

// ---------------------------------------------------------------- multi-region cast f32->bf16
struct CastArgs {
  const float* src[6];
  BF16* dst[6];
  long n[6];
};
__global__ void cast_multi_k(CastArgs a) {
  int r = blockIdx.y;
  long n = a.n[r];
  const float* __restrict__ x = a.src[r];
  BF16* __restrict__ y = a.dst[r];
  for (long i = ((long)blockIdx.x * 256 + threadIdx.x) * 4; i + 3 < n;
       i += (long)gridDim.x * 1024) {
    float4 v = *(const float4*)(x + i);
    y[i+0] = f2b(v.x); y[i+1] = f2b(v.y); y[i+2] = f2b(v.z); y[i+3] = f2b(v.w);
  }
}

// ---------------------------------------------------------------- NT GEMM body, m97-style LDS staging
// C[M][N] = A[M][K]*B[N][K]^T. 256 thr = 4 waves (2x2), 128x128 tile, BK=32.
// OUT_MODE: 0 = fp32 C;  2 = kv scatter -> Kt (scalar) / Vt transposed (8B packed);
//           3 = q RoPE+scale scatter -> Qt (scale includes log2(e) for exp2 softmax).
template<int OUT_MODE>
static __device__ __forceinline__ void gemm_body(
    const BF16* __restrict__ A, const BF16* __restrict__ B, void* __restrict__ C,
    int M, int N, int K, const float* __restrict__ cosb, const float* __restrict__ sinb,
    BF16* __restrict__ P1, BF16* __restrict__ P2, int bx, int by, BF16* As, BF16* Bs) {
  int tid = threadIdx.x, wave = tid >> 6, lane = tid & 63;
  int wr = wave >> 1, wc = wave & 1, lr = lane & 15, quad = lane >> 4;
  long m0 = (long)by * 128, n0 = (long)bx * 128;

  int c0 = wave*64 + lane, c1 = c0 + 256;
  const BF16* ga0 = A + (m0 + (c0>>2))*(long)K + (c0&3)*8;
  const BF16* ga1 = A + (m0 + (c1>>2))*(long)K + (c1&3)*8;
  long bn0 = n0 + (c0>>2); if (bn0 >= N) bn0 = N-1;
  long bn1 = n0 + (c1>>2); if (bn1 >= N) bn1 = N-1;
  const BF16* gb0 = B + bn0*(long)K + (c0&3)*8;
  const BF16* gb1 = B + bn1*(long)K + (c1&3)*8;
  BF16* la0 = As + wave*512;
  BF16* la1 = As + wave*512 + 2048;
  BF16* lb0 = Bs + wave*512;
  BF16* lb1 = Bs + wave*512 + 2048;

  floatx4 acc[4][4] = {};
  for (int k0 = 0; k0 < K; k0 += 32) {
    __syncthreads();
    load_lds16(ga0 + k0, la0);
    load_lds16(ga1 + k0, la1);
    load_lds16(gb0 + k0, lb0);
    load_lds16(gb1 + k0, lb1);
    __syncthreads();
    bf16x8 a[4], b[4];
#pragma unroll
    for (int i = 0; i < 4; i++) a[i] = *(const bf16x8*)(As + (wr*64 + i*16 + lr)*32 + quad*8);
#pragma unroll
    for (int j = 0; j < 4; j++) b[j] = *(const bf16x8*)(Bs + (wc*64 + j*16 + lr)*32 + quad*8);
#pragma unroll
    for (int i = 0; i < 4; i++)
#pragma unroll
      for (int j = 0; j < 4; j++)
        acc[i][j] = __builtin_amdgcn_mfma_f32_16x16x32_bf16(a[i], b[j], acc[i][j], 0, 0, 0);
  }

  long n0w = n0 + wc*64;
  // 192^-0.5 * log2(e): softmax runs in exp2 domain.
  const float SCALE_L2E = 0.104117546f;
#pragma unroll
  for (int i = 0; i < 4; i++) {
    long tok = m0 + wr*64 + i*16 + quad*4;   // 4 consecutive tokens (r=0..3)
    long bb = tok >> 11, s = tok & 2047;
    if (OUT_MODE == 0) {
#pragma unroll
      for (int r = 0; r < 4; r++) {
        long row = tok + r;
#pragma unroll
        for (int j = 0; j < 4; j++) {
          long col = n0w + j*16 + lr;
          if (col < N) ((float*)C)[row*(long)N + col] = acc[i][j][r];
        }
      }
    } else if (OUT_MODE == 2) {
#pragma unroll
      for (int j = 0; j < 4; j++) {
        long col = n0w + j*16 + lr;
        long h = col >> 8, d = col & 255;
        if (d < 128) {
#pragma unroll
          for (int r = 0; r < 4; r++)
            P1[((bb*16 + h)*2048 + s + r)*192 + d] = f2b(acc[i][j][r]);
        } else {
          // Vt transposed (B,H,128,2048): 4 consecutive tokens packed, 8B store
          ushort4 pk;
          pk.x = b2u(f2b(acc[i][j][0])); pk.y = b2u(f2b(acc[i][j][1]));
          pk.z = b2u(f2b(acc[i][j][2])); pk.w = b2u(f2b(acc[i][j][3]));
          *(ushort4*)(P2 + ((bb*16 + h)*128 + d - 128)*2048 + s) = pk;
        }
      }
    } else { // OUT_MODE == 3: q RoPE + scale -> Qt (B,H,S,192)
      bool rope = ((n0w % 192) == 128);
#pragma unroll
      for (int r = 0; r < 4; r++) {
        long row = tok + r;
#pragma unroll
        for (int j = 0; j < 4; j++) {
          long col = n0w + j*16 + lr;
          float x = acc[i][j][r], val;
          if (rope) {
            int id = j*16 + lr;
            float partner = acc[i][j^2][r];
            float rot = (j < 2) ? -partner : partner;
            val = x*cosb[row*64 + id] + rot*sinb[row*64 + id];
          } else {
            val = x;
          }
          long h = col / 192, d = col % 192;
          P1[((bb*16 + h)*2048 + s + r)*192 + d] = f2b(val * SCALE_L2E);
        }
      }
    }
  }
}

__global__ __launch_bounds__(256) void gemm0_k(const BF16* __restrict__ A, const BF16* __restrict__ B,
                                               float* __restrict__ C, int M, int N, int K) {
  __shared__ __align__(16) BF16 As[128*32];
  __shared__ __align__(16) BF16 Bs[128*32];
  gemm_body<0>(A, B, C, M, N, K, nullptr, nullptr, nullptr, nullptr,
               blockIdx.x, blockIdx.y, As, Bs);
}

// q_b (768 blocks, mode 3) + kv_b (1024 blocks, mode 2) in one launch: tails overlap.
__global__ __launch_bounds__(256) void gemm_qkv_k(const BF16* __restrict__ qan, const BF16* __restrict__ Wqb,
                                                  const BF16* __restrict__ kvn, const BF16* __restrict__ Wkvb,
                                                  const float* __restrict__ cosb, const float* __restrict__ sinb,
                                                  BF16* __restrict__ Qt, BF16* __restrict__ Kt,
                                                  BF16* __restrict__ Vt) {
  __shared__ __align__(16) BF16 As[128*32];
  __shared__ __align__(16) BF16 Bs[128*32];
  int bid = blockIdx.x;
  if (bid < 768) {
    gemm_body<3>(qan, Wqb, nullptr, 4096, 3072, 1536, cosb, sinb, Qt, nullptr,
                 bid % 24, bid / 24, As, Bs);
  } else {
    bid -= 768;
    gemm_body<2>(kvn, Wkvb, nullptr, 4096, 4096, 512, nullptr, nullptr, Kt, Vt,
                 bid % 32, bid / 32, As, Bs);
  }
}

// ---------------------------------------------------------------- fused: rmsnorm(1536) + rmsnorm(512) + k_rot RoPE
// One block per token row of qakv (stride 2112: [q_a 1536 | ckv 512 | krot 64]).
__global__ __launch_bounds__(256) void norms_k(const float* __restrict__ qakv,
                                               const float* __restrict__ qw, const float* __restrict__ kw,
                                               const float* __restrict__ cosb, const float* __restrict__ sinb,
                                               BF16* __restrict__ qan, BF16* __restrict__ kvn,
                                               BF16* __restrict__ Kt) {
  long row = blockIdx.x;
  const float* xr = qakv + row * 2112;
  int tid = threadIdx.x;
  __shared__ float red[4];
  // ---- rmsnorm D=1536 -> qan
  {
    float ss = 0.f;
    for (int i = tid*4; i < 1536; i += 1024) {
      float4 v = *(const float4*)(xr + i);
      ss += v.x*v.x + v.y*v.y + v.z*v.z + v.w*v.w;
    }
#pragma unroll
    for (int off = 32; off > 0; off >>= 1) ss += __shfl_down(ss, off);
    if ((tid & 63) == 0) red[tid >> 6] = ss;
    __syncthreads();
    float rs = rsqrtf((red[0]+red[1]+red[2]+red[3]) / 1536.f + 1e-6f);
    BF16* yr = qan + row * 1536;
    for (int i = tid*4; i < 1536; i += 1024) {
      float4 v = *(const float4*)(xr + i);
      yr[i+0] = f2b(v.x * qw[i+0] * rs);
      yr[i+1] = f2b(v.y * qw[i+1] * rs);
      yr[i+2] = f2b(v.z * qw[i+2] * rs);
      yr[i+3] = f2b(v.w * qw[i+3] * rs);
    }
  }
  __syncthreads();
  // ---- rmsnorm D=512 (offset 1536) -> kvn
  {
    float ss = 0.f;
    for (int i = tid*4; i < 512; i += 1024) {
      float4 v = *(const float4*)(xr + 1536 + i);
      ss += v.x*v.x + v.y*v.y + v.z*v.z + v.w*v.w;
    }
#pragma unroll
    for (int off = 32; off > 0; off >>= 1) ss += __shfl_down(ss, off);
    if ((tid & 63) == 0) red[tid >> 6] = ss;
    __syncthreads();
    float rs = rsqrtf((red[0]+red[1]+red[2]+red[3]) / 512.f + 1e-6f);
    BF16* yr = kvn + row * 512;
    for (int i = tid*4; i < 512; i += 1024) {
      float4 v = *(const float4*)(xr + 1536 + i);
      yr[i+0] = f2b(v.x * kw[i+0] * rs);
      yr[i+1] = f2b(v.y * kw[i+1] * rs);
      yr[i+2] = f2b(v.z * kw[i+2] * rs);
      yr[i+3] = f2b(v.w * kw[i+3] * rs);
    }
  }
  // ---- k_rot RoPE -> Kt[...,128:192] broadcast to all 16 heads
  if (tid < 64) {
    int i = tid;
    const float* kr = xr + 2048;
    float x = kr[i];
    float rot = (i < 32) ? -kr[i + 32] : kr[i - 32];
    BF16 v = f2b(x * cosb[row*64 + i] + rot * sinb[row*64 + i]);
    long b = row >> 11, s = row & 2047;
    long base = ((b*16)*2048 + s)*192 + 128 + i;
#pragma unroll
    for (int h = 0; h < 16; h++) Kt[base + (long)h*2048*192] = v;
  }
}

// ---------------------------------------------------------------- causal flash attention
// grid 256, 512 threads (8 waves); g = F&31 = (b,h) group (XCD pin: F%8 = g%8);
// j = F>>5 in 0..7: block handles 128-row q-tile pair {j, 15-j} -> 34 uniform
// k-tile iters. Each wave owns 16 q-rows; waves fully below the diagonal skip
// compute (barriers stay unconditional). Q prescaled by 192^-0.5*log2e; V is
// (B,H,128,S) transposed so staging is b128-only, bank-uniform.
// Softmax reductions: DPP row all-reduce (VALU pipe, no LDS-swizzle latency).
// Staging: depth-1 register prefetch with STATIC register arrays (r9's dynamic
// kt&1 indexing demoted the buffers to scratch -> 13x regression).
#define LK 200
#define LV 72
#define LP 72
__global__ __launch_bounds__(512) void flash_k(const BF16* __restrict__ Qt, const BF16* __restrict__ Kt,
                                               const BF16* __restrict__ Vt, BF16* __restrict__ O) {
  __shared__ __align__(16) BF16 Ks[64*LK];    // K tile [kpos][d]        25.6 KB
  __shared__ __align__(16) BF16 Vs[128*LV];   // V^T tile [vd][kpos]     18.4 KB
  __shared__ __align__(16) BF16 Ps[8][16*LP]; // per-wave P [q16][kpos]  18.4 KB
  int tid = threadIdx.x, wave = tid >> 6, lane = tid & 63;
  int lr = lane & 15, quad = lane >> 4;
  int F = blockIdx.x;
  int g = F & 31, j = F >> 5;
  int h = g & 15, b = g >> 4;
  const BF16* Qb = Qt + ((long)(b*16 + h) * 2048) * 192;
  const BF16* Kb = Kt + ((long)(b*16 + h) * 2048) * 192;
  const BF16* Vb = Vt + ((long)(b*16 + h) * 128) * 2048;
  const float NEG_INF = -__builtin_inff();

  // staging geometry: K 1536 chunks / 512 thr = 3; V 1024 chunks / 512 thr = 2
  int krow[3], kcol[3];
#pragma unroll
  for (int i = 0; i < 3; i++) {
    int c = tid + 512*i;
    krow[i] = c / 24; kcol[i] = (c % 24) * 8;
  }
  int vrow[2], vcol[2];
#pragma unroll
  for (int i = 0; i < 2; i++) {
    int c = tid + 512*i;
    vrow[i] = c >> 3; vcol[i] = (c & 7) * 8;
  }

  bf16x8 kreg[3], vreg[2];   // depth-1, statically indexed
  auto stage_load = [&](int k0) {
#pragma unroll
    for (int i = 0; i < 3; i++)
      kreg[i] = *(const bf16x8*)(Kb + (long)(k0 + krow[i])*192 + kcol[i]);
#pragma unroll
    for (int i = 0; i < 2; i++)
      vreg[i] = *(const bf16x8*)(Vb + (long)vrow[i]*2048 + k0 + vcol[i]);
  };
  auto stage_store = [&]() {
#pragma unroll
    for (int i = 0; i < 3; i++)
      *(bf16x8*)(Ks + krow[i]*LK + kcol[i]) = kreg[i];
#pragma unroll
    for (int i = 0; i < 2; i++)
      *(bf16x8*)(Vs + vrow[i]*LV + vcol[i]) = vreg[i];
  };

  for (int half = 0; half < 2; half++) {
    int qt = (half == 0) ? j : 15 - j;
    int q0 = qt * 128;
    int wq0 = q0 + wave*16;   // this wave's first q-row
    bf16x8 qf[6];
    {
      const BF16* qp = Qb + (long)(wq0 + lr) * 192 + quad*8;
#pragma unroll
      for (int f = 0; f < 6; f++) qf[f] = *(const bf16x8*)(qp + f*32);
    }
    float m_i[4], l_i[4];
#pragma unroll
    for (int r = 0; r < 4; r++) { m_i[r] = NEG_INF; l_i[r] = 0.f; }
    floatx4 o_acc[8] = {};
    int nk = 2*qt + 2;
    stage_load(0);
    for (int kt = 0; kt < nk; kt++) {
      __syncthreads();   // prev-iter LDS reads complete
      stage_store();
      __syncthreads();
      if (kt + 1 < nk) stage_load((kt + 1) * 64);  // prefetch overlaps compute
      if (kt*64 > wq0 + 15) continue;  // wave fully above diagonal (masked out)
      floatx4 st[4];
#pragma unroll
      for (int t = 0; t < 4; t++) {
        floatx4 c = {};
#pragma unroll
        for (int f = 0; f < 6; f++) {
          bf16x8 kf = *(const bf16x8*)(Ks + (t*16+lr)*LK + f*32 + quad*8);
          c = __builtin_amdgcn_mfma_f32_16x16x32_bf16(qf[f], kf, c, 0, 0, 0);
        }
        st[t] = c;
      }
      float mt[4];
#pragma unroll
      for (int r = 0; r < 4; r++) mt[r] = NEG_INF;
      if (kt*64 + 63 > wq0) { // diagonal k-tile for this wave: causal mask
        int rbase = wq0 + quad*4 - kt*64;  // row - kbase
#pragma unroll
        for (int t = 0; t < 4; t++) {
          int coff = t*16 + lr;
#pragma unroll
          for (int r = 0; r < 4; r++) {
            float sc = st[t][r];
            if (coff > rbase + r) sc = NEG_INF;
            st[t][r] = sc;
            mt[r] = fmaxf(mt[r], sc);
          }
        }
      } else {
#pragma unroll
        for (int t = 0; t < 4; t++)
#pragma unroll
          for (int r = 0; r < 4; r++) mt[r] = fmaxf(mt[r], st[t][r]);
      }
#pragma unroll
      for (int r = 0; r < 4; r++) mt[r] = row_allmax(mt[r]);
      float alpha[4], rsum[4];
#pragma unroll
      for (int r = 0; r < 4; r++) {
        float mn = fmaxf(m_i[r], mt[r]);
        alpha[r] = fast_exp2(m_i[r] - mn);
        m_i[r] = mn;
        rsum[r] = 0.f;
      }
#pragma unroll
      for (int t = 0; t < 4; t++)
#pragma unroll
        for (int r = 0; r < 4; r++) {
          float p = fast_exp2(st[t][r] - m_i[r]);
          st[t][r] = p;
          rsum[r] += p;
        }
#pragma unroll
      for (int r = 0; r < 4; r++) rsum[r] = row_allsum(rsum[r]);
#pragma unroll
      for (int r = 0; r < 4; r++) l_i[r] = l_i[r]*alpha[r] + rsum[r];
#pragma unroll
      for (int v = 0; v < 8; v++)
#pragma unroll
        for (int r = 0; r < 4; r++) o_acc[v][r] *= alpha[r];
      // P (C-layout) -> wave-private LDS -> A-layout (no barrier: wave-level ordering)
#pragma unroll
      for (int t = 0; t < 4; t++)
#pragma unroll
        for (int r = 0; r < 4; r++)
          Ps[wave][(quad*4 + r)*LP + t*16 + lr] = f2b(st[t][r]);
#pragma unroll
      for (int kc = 0; kc < 2; kc++) {
        bf16x8 pa = *(const bf16x8*)(&Ps[wave][lr*LP + kc*32 + quad*8]);
#pragma unroll
        for (int v = 0; v < 8; v++) {
          bf16x8 vf = *(const bf16x8*)(&Vs[(v*16+lr)*LV + kc*32 + quad*8]);
          o_acc[v] = __builtin_amdgcn_mfma_f32_16x16x32_bf16(pa, vf, o_acc[v], 0, 0, 0);
        }
      }
    }
    // epilogue: attn out (B,S,H*128) bf16
    long rowb = wq0 + quad*4;
#pragma unroll
    for (int v = 0; v < 8; v++)
#pragma unroll
      for (int r = 0; r < 4; r++) {
        long row = rowb + r;
        O[((long)b*2048 + row)*2048 + h*128 + v*16 + lr] = f2b(o_acc[v][r] / l_i[r]);
      }
  }
}

// ---------------------------------------------------------------- launch
extern "C" void kernel_launch(void* const* d_in, const int* in_sizes, int n_in,
                              void* d_out, int out_size, void* d_ws, size_t ws_size,
                              hipStream_t stream) {
  const float* hidden      = (const float*)d_in[0];
  const float* cosb        = (const float*)d_in[1];
  const float* sinb        = (const float*)d_in[2];
  const float* q_a_W       = (const float*)d_in[3];
  const float* q_a_norm_w  = (const float*)d_in[4];
  const float* q_b_W       = (const float*)d_in[5];
  const float* kv_a_W      = (const float*)d_in[6];
  const float* kv_a_norm_w = (const float*)d_in[7];
  const float* kv_b_W      = (const float*)d_in[8];
  const float* o_W         = (const float*)d_in[9];
  float* out = (float*)d_out;

  const int Mrows = 4096;

  char* ws = (char*)d_ws; size_t off = 0;
  auto alloc = [&](size_t bytes) -> void* {
    void* p = ws + off; off = (off + bytes + 255) & ~(size_t)255; return p;
  };
  BF16* hb    = (BF16*)alloc((size_t)4096*2048*2);
  BF16* Wqakv = (BF16*)alloc((size_t)2112*2048*2);   // rows 0..1536 = q_a_W, 1536..2112 = kv_a_W
  BF16* Wqb   = (BF16*)alloc((size_t)3072*1536*2);
  BF16* Wkvb  = (BF16*)alloc((size_t)4096*512*2);
  BF16* Wo    = (BF16*)alloc((size_t)2048*2048*2);
  float* qakv = (float*)alloc((size_t)4096*2112*4);  // cols 0..1536 = q_a out, 1536..2112 = ckv
  BF16* qan   = (BF16*)alloc((size_t)4096*1536*2);
  BF16* kvn   = (BF16*)alloc((size_t)4096*512*2);
  BF16* Qt    = (BF16*)alloc((size_t)2*16*2048*192*2);
  BF16* Kt    = (BF16*)alloc((size_t)2*16*2048*192*2);
  BF16* Vt    = (BF16*)alloc((size_t)2*16*128*2048*2); // transposed (B,H,128,S)
  BF16* attn  = (BF16*)alloc((size_t)4096*2048*2);

  CastArgs ca;
  ca.src[0] = hidden;  ca.dst[0] = hb;                 ca.n[0] = (long)4096*2048;
  ca.src[1] = q_a_W;   ca.dst[1] = Wqakv;              ca.n[1] = (long)1536*2048;
  ca.src[2] = kv_a_W;  ca.dst[2] = Wqakv + (long)1536*2048; ca.n[2] = (long)576*2048;
  ca.src[3] = q_b_W;   ca.dst[3] = Wqb;                ca.n[3] = (long)3072*1536;
  ca.src[4] = kv_b_W;  ca.dst[4] = Wkvb;               ca.n[4] = (long)4096*512;
  ca.src[5] = o_W;     ca.dst[5] = Wo;                 ca.n[5] = (long)2048*2048;
  cast_multi_k<<<dim3(1024, 6), dim3(256), 0, stream>>>(ca);

  // [q_a | ckv] = hidden @ [q_a_W | kv_a_W].T  (4096 x 2112, K=2048), fp32
  gemm0_k<<<dim3(17, 32), dim3(256), 0, stream>>>(hb, Wqakv, qakv, Mrows, 2112, 2048);

  // fused rmsnorms + k_rot RoPE
  norms_k<<<dim3(4096), dim3(256), 0, stream>>>(qakv, q_a_norm_w, kv_a_norm_w,
                                                cosb, sinb, qan, kvn, Kt);

  // q_b (RoPE+scale -> Qt) and kv_b (scatter -> Kt / Vt^T) in one launch
  gemm_qkv_k<<<dim3(1792), dim3(256), 0, stream>>>(qan, Wqb, kvn, Wkvb, cosb, sinb, Qt, Kt, Vt);

  flash_k<<<dim3(256), dim3(512), 0, stream>>>(Qt, Kt, Vt, attn);

  // out = attn @ o_W.T (4096x2048, K=2048), fp32 -> d_out
  gemm0_k<<<dim3(16, 32), dim3(256), 0, stream>>>(attn, Wo, out, Mrows, 2048, 2048);
}